// Round 2
// baseline (13.300 us; speedup 1.0000x reference)
//
#include <hip/hip_runtime.h>
#include <math.h>

// (L, B, N, C) = (4, 16, 4096, 512), fp32. Only token n = N-1 contributes.
#define L_DIM 4
#define B_DIM 16
#define N_DIM 4096
#define C_DIM 512
#define NROWS (L_DIM * B_DIM)   // 64

// Single-block fused kernel: 1024 threads = 16 waves; wave w owns rows
// 4w..4w+3. Each lane owns 8 channels of each row (two float4 loads per
// tensor, coalesced 1 KiB per wave instruction). All 16 loads issued up
// front to overlap HBM latency. Softmax stats via 64-lane shuffle trees,
// KL partial deferred to one tree, cross-wave combine via LDS.
__global__ __launch_bounds__(1024) void kd_fused_kernel(
    const float* __restrict__ g1, const float* __restrict__ g2,
    float* __restrict__ out)
{
    const int tid  = threadIdx.x;
    const int wave = tid >> 6;     // 0..15
    const int lane = tid & 63;     // 0..63

    float4 A0[4], A1[4], B0[4], B1[4];
    #pragma unroll
    for (int r = 0; r < 4; ++r) {
        const int row = wave * 4 + r;
        const size_t base = ((size_t)row * N_DIM + (N_DIM - 1)) * (size_t)C_DIM;
        A0[r] = *(const float4*)(g1 + base + 4 * lane);
        A1[r] = *(const float4*)(g1 + base + 256 + 4 * lane);
        B0[r] = *(const float4*)(g2 + base + 4 * lane);
        B1[r] = *(const float4*)(g2 + base + 256 + 4 * lane);
    }

    float acc = 0.f;   // lane-local sym-KL partial over this wave's 4 rows

    #pragma unroll
    for (int r = 0; r < 4; ++r) {
        float x1[8] = {A0[r].x, A0[r].y, A0[r].z, A0[r].w,
                       A1[r].x, A1[r].y, A1[r].z, A1[r].w};
        float x2[8] = {B0[r].x, B0[r].y, B0[r].z, B0[r].w,
                       B1[r].x, B1[r].y, B1[r].z, B1[r].w};

        float m1 = -INFINITY, m2 = -INFINITY;
        #pragma unroll
        for (int k = 0; k < 8; ++k) {
            x1[k] *= 0.5f;  x2[k] *= 0.5f;      // x = guidance / 2
            m1 = fmaxf(m1, x1[k]);
            m2 = fmaxf(m2, x2[k]);
        }
        #pragma unroll
        for (int off = 32; off > 0; off >>= 1) {
            m1 = fmaxf(m1, __shfl_xor(m1, off, 64));
            m2 = fmaxf(m2, __shfl_xor(m2, off, 64));
        }

        float s1 = 0.f, s2 = 0.f;
        #pragma unroll
        for (int k = 0; k < 8; ++k) {
            s1 += __expf(x1[k] - m1);
            s2 += __expf(x2[k] - m2);
        }
        #pragma unroll
        for (int off = 32; off > 0; off >>= 1) {
            s1 += __shfl_xor(s1, off, 64);
            s2 += __shfl_xor(s2, off, 64);
        }
        const float lse1 = m1 + __logf(s1);
        const float lse2 = m2 + __logf(s2);

        // (p1 - p2) * (lp1 - lp2) summed over channels
        #pragma unroll
        for (int k = 0; k < 8; ++k) {
            const float lp1 = x1[k] - lse1;
            const float lp2 = x2[k] - lse2;
            acc += (__expf(lp1) - __expf(lp2)) * (lp1 - lp2);
        }
    }

    // one reduction tree for the deferred KL partial
    #pragma unroll
    for (int off = 32; off > 0; off >>= 1)
        acc += __shfl_xor(acc, off, 64);

    __shared__ float wsum[16];
    if (lane == 0) wsum[wave] = acc;
    __syncthreads();

    if (wave == 0) {
        float v = (lane < 16) ? wsum[lane] : 0.f;
        #pragma unroll
        for (int off = 8; off > 0; off >>= 1)
            v += __shfl_xor(v, off, 64);
        if (lane == 0)
            out[0] = v * (0.5f / (float)L_DIM);
    }
}

extern "C" void kernel_launch(void* const* d_in, const int* in_sizes, int n_in,
                              void* d_out, int out_size, void* d_ws, size_t ws_size,
                              hipStream_t stream) {
    const float* g1 = (const float*)d_in[0];
    const float* g2 = (const float*)d_in[1];
    float* out      = (float*)d_out;

    kd_fused_kernel<<<dim3(1), dim3(1024), 0, stream>>>(g1, g2, out);
}